// Round 13
// baseline (353.185 us; speedup 1.0000x reference)
//
#include <hip/hip_runtime.h>

static constexpr int D = 96;       // hidden size
static constexpr int G3 = 3 * D;   // 288 gate rows
static constexpr int NSTEPS = 4;   // GGNN propagation steps
static constexpr int NT = 18;      // 288/16 col-tiles per weight matrix
static constexpr int SCAN_BLK = 1024;  // elements per scan block
static constexpr int SLP = 104;    // s-tile LDS row pad (fp16)

typedef __attribute__((ext_vector_type(8))) _Float16 f16x8;  // 8 fp16 (4 VGPRs)
typedef __attribute__((ext_vector_type(4))) _Float16 f16x4;
typedef __attribute__((ext_vector_type(4))) float f32x4;     // MFMA C/D frag

// A-fragment for mfma_f32_16x16x32_f16 from fp16 row-major [*,96]:
// lane holds row=r0+(lane&15), k = kc*32 + (lane>>4)*8 .. +7 -> 16B contiguous
// rows clamped to n-1 (results for clamped rows are discarded by store guard)
__device__ __forceinline__ f16x8 load_a_frag_clamp(const _Float16* __restrict__ base,
                                                   int r0, int lane, int kc, int n) {
  int row = r0 + (lane & 15);
  if (row >= n) row = n - 1;
  int k0 = kc * 32 + ((lane >> 4) << 3);
  return *(const f16x8*)(base + (size_t)row * D + k0);
}

// Swizzled B-fragment: slot (t,kc) holds 64 lanes' f16x8 contiguously (1KB)
__device__ __forceinline__ f16x8 load_b_swz(const _Float16* __restrict__ W,
                                            int t, int kc, int lane) {
  return *(const f16x8*)(W + (((size_t)t * 3 + kc) * 64 + lane) * 8);
}

// ---------- one-time prep ----------

__global__ void convert_x_kernel(const float* __restrict__ x,
                                 _Float16* __restrict__ h, int total4) {
  int i = blockIdx.x * blockDim.x + threadIdx.x;
  if (i >= total4) return;
  float4 v = ((const float4*)x)[i];
  f16x4 o;
  o[0] = (_Float16)v.x; o[1] = (_Float16)v.y;
  o[2] = (_Float16)v.z; o[3] = (_Float16)v.w;
  *(f16x4*)(h + (size_t)i * 4) = o;
}

// W_x[r][k] = sum_c W_ih[r][c] * W_e[c][k]; bxe[r] = sum_c W_ih[r][c] * b_e[c]
__global__ void compute_wx_kernel(const float* __restrict__ Wih,
                                  const float* __restrict__ We,
                                  const float* __restrict__ be,
                                  float* __restrict__ Wx,
                                  float* __restrict__ bxe) {
  int idx = blockIdx.x * blockDim.x + threadIdx.x;
  if (idx < G3 * D) {
    int r = idx / D, k = idx - r * D;
    float acc = 0.f;
    for (int c = 0; c < D; ++c) acc += Wih[r * D + c] * We[c * D + k];
    Wx[idx] = acc;
  } else if (idx < G3 * D + G3) {
    int r = idx - G3 * D;
    float acc = 0.f;
    for (int c = 0; c < D; ++c) acc += Wih[r * D + c] * be[c];
    bxe[r] = acc;
  }
}

// convert Wx/Whh to fp16 in MFMA-fragment (swizzled) order
__global__ void swizzle_f16_kernel(const float* __restrict__ Wx,
                                   const float* __restrict__ Whh,
                                   _Float16* __restrict__ WxF,
                                   _Float16* __restrict__ WhhF) {
  int idx = blockIdx.x * blockDim.x + threadIdx.x;
  if (idx >= 2 * NT * 3 * 64) return;
  int mat = idx / (NT * 3 * 64);
  int rem = idx - mat * (NT * 3 * 64);
  int t = rem / (3 * 64);
  int rem2 = rem - t * (3 * 64);
  int kc = rem2 >> 6;
  int lane = rem2 & 63;
  int c = t * 16 + (lane & 15);
  int k0 = kc * 32 + ((lane >> 4) << 3);
  const float* W = mat ? Whh : Wx;
  _Float16* dF = mat ? WhhF : WxF;
  f16x8 o;
#pragma unroll
  for (int j = 0; j < 8; ++j) o[j] = (_Float16)W[(size_t)c * D + k0 + j];
  *(f16x8*)(dF + (((size_t)t * 3 + kc) * 64 + lane) * 8) = o;
}

// ---------- CSR build ----------

__global__ void hist_kernel(const int* __restrict__ dst, int* __restrict__ counts, int E) {
  int e = blockIdx.x * blockDim.x + threadIdx.x;
  if (e < E) atomicAdd(&counts[dst[e]], 1);
}

__global__ void partial_sum_kernel(const int* __restrict__ counts,
                                   int* __restrict__ blk_sums, int n) {
  __shared__ int red[256];
  int base = blockIdx.x * SCAN_BLK;
  int tid = threadIdx.x;
  int s = 0;
#pragma unroll
  for (int j = 0; j < 4; ++j) {
    int i = base + j * 256 + tid;
    if (i < n) s += counts[i];
  }
  red[tid] = s;
  __syncthreads();
  for (int off = 128; off > 0; off >>= 1) {
    if (tid < off) red[tid] += red[tid + off];
    __syncthreads();
  }
  if (tid == 0) blk_sums[blockIdx.x] = red[0];
}

__global__ void scan_offsets_kernel(const int* __restrict__ blk_sums,
                                    int* __restrict__ blk_off,
                                    int* __restrict__ row_ptr, int nb, int n) {
  __shared__ int lds[64];
  int tid = threadIdx.x;
  if (tid < nb) lds[tid] = blk_sums[tid];
  __syncthreads();
  if (tid == 0) {
    int run = 0;
    for (int i = 0; i < nb; ++i) { blk_off[i] = run; run += lds[i]; }
    row_ptr[n] = run;
  }
}

__global__ void block_scan_kernel(const int* __restrict__ counts,
                                  const int* __restrict__ blk_off,
                                  int* __restrict__ row_ptr, int n) {
  __shared__ int red[256];
  int base = blockIdx.x * SCAN_BLK;
  int tid = threadIdx.x;
  int i0 = base + tid * 4;
  int v0 = 0, v1 = 0, v2 = 0, v3 = 0;
  if (i0 + 3 < n) {
    int4 c = *(const int4*)(counts + i0);
    v0 = c.x; v1 = c.y; v2 = c.z; v3 = c.w;
  } else {
    if (i0 < n) v0 = counts[i0];
    if (i0 + 1 < n) v1 = counts[i0 + 1];
    if (i0 + 2 < n) v2 = counts[i0 + 2];
  }
  int tsum = v0 + v1 + v2 + v3;
  red[tid] = tsum;
  __syncthreads();
  for (int off = 1; off < 256; off <<= 1) {
    int t = (tid >= off) ? red[tid - off] : 0;
    __syncthreads();
    red[tid] += t;
    __syncthreads();
  }
  int excl = blk_off[blockIdx.x] + red[tid] - tsum;
  if (i0 < n) row_ptr[i0] = excl;
  if (i0 + 1 < n) row_ptr[i0 + 1] = excl + v0;
  if (i0 + 2 < n) row_ptr[i0 + 2] = excl + v0 + v1;
  if (i0 + 3 < n) row_ptr[i0 + 3] = excl + v0 + v1 + v2;
}

// csr_src stored as uint16 (n < 65536): halves scatter-write traffic
__global__ void fill_kernel(const int* __restrict__ src, const int* __restrict__ dst,
                            const int* __restrict__ row_ptr,
                            int* __restrict__ fillc,
                            unsigned short* __restrict__ csr_src, int E) {
  int e = blockIdx.x * blockDim.x + threadIdx.x;
  if (e >= E) return;
  int t = dst[e];
  int pos = row_ptr[t] + atomicAdd(&fillc[t], 1);
  csr_src[pos] = (unsigned short)src[e];
}

// ---------- fused per-step kernel ----------

// Fused aggregate + GRU. Block = 32 rows, 6 waves (384 threads), LDS = 6.7 KB.
// Phase 1: 32 rows x 12 threads gather neighbor sums into sl (f16x8, fp32 accum).
// Phase 2: wave w owns col-tile w (cols w*16..w*16+15) and computes ALL THREE
//          gates for it (weight tiles w, 6+w, 12+w of both Wx and Whh), row-tiles
//          processed serially. Epilogue fully in-register -> direct fp16 store.
__global__ __launch_bounds__(384) void gru_fused_kernel(
    const _Float16* __restrict__ h, _Float16* __restrict__ hout,
    const int* __restrict__ row_ptr, const unsigned short* __restrict__ csr_src,
    const _Float16* __restrict__ WxF, const _Float16* __restrict__ WhhF,
    const float* __restrict__ bxe, const float* __restrict__ bih,
    const float* __restrict__ bhh, int n) {
  __shared__ _Float16 sl[32 * SLP];   // 6.7 KB aggregated s tile
  int r0 = blockIdx.x << 5;   // 32 rows per block
  int tid = threadIdx.x;
  int w = tid >> 6;
  int lane = tid & 63;

  // ---- phase 1: gather (12 threads/row, one f16x8 chunk each; 8-deep MLP) ----
  {
    int row = tid / 12;        // 0..31
    int part = tid - row * 12; // chunk of 8 fp16
    int grow = r0 + row;
    float acc[8];
#pragma unroll
    for (int j = 0; j < 8; ++j) acc[j] = 0.f;
    if (grow < n) {
      int beg = row_ptr[grow], end = row_ptr[grow + 1];
      const _Float16* hp = h + (size_t)part * 8;
      int e = beg;
      for (; e + 7 < end; e += 8) {
        f16x8 v0 = *(const f16x8*)(hp + (size_t)csr_src[e] * D);
        f16x8 v1 = *(const f16x8*)(hp + (size_t)csr_src[e + 1] * D);
        f16x8 v2 = *(const f16x8*)(hp + (size_t)csr_src[e + 2] * D);
        f16x8 v3 = *(const f16x8*)(hp + (size_t)csr_src[e + 3] * D);
        f16x8 v4 = *(const f16x8*)(hp + (size_t)csr_src[e + 4] * D);
        f16x8 v5 = *(const f16x8*)(hp + (size_t)csr_src[e + 5] * D);
        f16x8 v6 = *(const f16x8*)(hp + (size_t)csr_src[e + 6] * D);
        f16x8 v7 = *(const f16x8*)(hp + (size_t)csr_src[e + 7] * D);
#pragma unroll
        for (int j = 0; j < 8; ++j)
          acc[j] += (((float)v0[j] + (float)v1[j]) + ((float)v2[j] + (float)v3[j])) +
                    (((float)v4[j] + (float)v5[j]) + ((float)v6[j] + (float)v7[j]));
      }
      if (e + 3 < end) {
        f16x8 v0 = *(const f16x8*)(hp + (size_t)csr_src[e] * D);
        f16x8 v1 = *(const f16x8*)(hp + (size_t)csr_src[e + 1] * D);
        f16x8 v2 = *(const f16x8*)(hp + (size_t)csr_src[e + 2] * D);
        f16x8 v3 = *(const f16x8*)(hp + (size_t)csr_src[e + 3] * D);
#pragma unroll
        for (int j = 0; j < 8; ++j)
          acc[j] += ((float)v0[j] + (float)v1[j]) + ((float)v2[j] + (float)v3[j]);
        e += 4;
      }
      for (; e < end; ++e) {
        f16x8 v = *(const f16x8*)(hp + (size_t)csr_src[e] * D);
#pragma unroll
        for (int j = 0; j < 8; ++j) acc[j] += (float)v[j];
      }
    }
    f16x8 o;
#pragma unroll
    for (int j = 0; j < 8; ++j) o[j] = (_Float16)acc[j];
    *(f16x8*)&sl[row * SLP + part * 8] = o;
  }
  __syncthreads();

  // ---- phase 2: per-wave col-tile GRU (all gates in-register) ----
  const int t = w;                 // col-tile 0..5
  const int col_l = lane & 15;
  const int rq = (lane >> 4) << 2;
  const int col = t * 16 + col_l;

  // per-col constants (same for both row-tiles)
  const float br  = bih[col] + bhh[col];
  const float bz  = bih[D + col] + bhh[D + col];
  const float bxn = bih[2 * D + col];
  const float bhn = bhh[2 * D + col];
  const float xr = bxe[col], xz = bxe[D + col], xnc = bxe[2 * D + col];

#pragma unroll
  for (int rt = 0; rt < 2; ++rt) {
    const int rbase = r0 + rt * 16;
    f16x8 aS[3], aH[3];
#pragma unroll
    for (int kc = 0; kc < 3; ++kc) {
      int k0 = kc * 32 + ((lane >> 4) << 3);
      aS[kc] = *(const f16x8*)&sl[(rt * 16 + (lane & 15)) * SLP + k0];
      aH[kc] = load_a_frag_clamp(h, rbase, lane, kc, n);
    }
    f32x4 accR = {0.f, 0.f, 0.f, 0.f};
    f32x4 accZ = {0.f, 0.f, 0.f, 0.f};
    f32x4 accXN = {0.f, 0.f, 0.f, 0.f};
    f32x4 accHN = {0.f, 0.f, 0.f, 0.f};
#pragma unroll
    for (int kc = 0; kc < 3; ++kc) {
      accR  = __builtin_amdgcn_mfma_f32_16x16x32_f16(aS[kc], load_b_swz(WxF,  t,      kc, lane), accR, 0, 0, 0);
      accR  = __builtin_amdgcn_mfma_f32_16x16x32_f16(aH[kc], load_b_swz(WhhF, t,      kc, lane), accR, 0, 0, 0);
      accZ  = __builtin_amdgcn_mfma_f32_16x16x32_f16(aS[kc], load_b_swz(WxF,  6 + t,  kc, lane), accZ, 0, 0, 0);
      accZ  = __builtin_amdgcn_mfma_f32_16x16x32_f16(aH[kc], load_b_swz(WhhF, 6 + t,  kc, lane), accZ, 0, 0, 0);
      accXN = __builtin_amdgcn_mfma_f32_16x16x32_f16(aS[kc], load_b_swz(WxF,  12 + t, kc, lane), accXN, 0, 0, 0);
      accHN = __builtin_amdgcn_mfma_f32_16x16x32_f16(aH[kc], load_b_swz(WhhF, 12 + t, kc, lane), accHN, 0, 0, 0);
    }
    // in-register epilogue: C/D layout col=lane&15, row=(lane>>4)*4+q
#pragma unroll
    for (int q = 0; q < 4; ++q) {
      int grow = rbase + rq + q;
      if (grow < n) {
        float degf = (float)(row_ptr[grow + 1] - row_ptr[grow]);
        float rg = 1.0f / (1.0f + __expf(-(accR[q] + br + degf * xr)));
        float zg = 1.0f / (1.0f + __expf(-(accZ[q] + bz + degf * xz)));
        float ng = tanhf(accXN[q] + bxn + degf * xnc + rg * (accHN[q] + bhn));
        float hv = (float)h[(size_t)grow * D + col];
        hout[(size_t)grow * D + col] = (_Float16)((1.0f - zg) * ng + zg * hv);
      }
    }
  }
}

// logits[i,c] = sum_k elu(h[i,k]) * Wfc[c,k] + bfc[c]
__global__ void head_kernel(const _Float16* __restrict__ h,
                            const float* __restrict__ Wfc,
                            const float* __restrict__ bfc,
                            float* __restrict__ out,
                            int n, int C) {
  int idx = blockIdx.x * blockDim.x + threadIdx.x;
  if (idx >= n * C) return;
  int i = idx / C;
  int c = idx - i * C;
  const _Float16* hr = h + (size_t)i * D;
  const float* wr = Wfc + (size_t)c * D;
  float acc = bfc[c];
#pragma unroll 8
  for (int k = 0; k < D; ++k) {
    float hv = (float)hr[k];
    float e = hv > 0.0f ? hv : (__expf(hv) - 1.0f);
    acc += e * wr[k];
  }
  out[idx] = acc;
}

extern "C" void kernel_launch(void* const* d_in, const int* in_sizes, int n_in,
                              void* d_out, int out_size, void* d_ws, size_t ws_size,
                              hipStream_t stream) {
  const float* x    = (const float*)d_in[0];
  const int*   src  = (const int*)d_in[1];
  const int*   dst  = (const int*)d_in[2];
  const float* W_e  = (const float*)d_in[3];
  const float* b_e  = (const float*)d_in[4];
  const float* W_ih = (const float*)d_in[5];
  const float* W_hh = (const float*)d_in[6];
  const float* b_ih = (const float*)d_in[7];
  const float* b_hh = (const float*)d_in[8];
  const float* W_fc = (const float*)d_in[9];
  const float* b_fc = (const float*)d_in[10];

  const int n = in_sizes[0] / D;   // 50000
  const int E = in_sizes[1];       // 800000
  const int C = out_size / n;      // 10

  // ws layout (fp16 state):
  _Float16* hA = (_Float16*)d_ws;                 // n*D fp16
  _Float16* hB = hA + (size_t)n * D;              // n*D fp16
  float* Wx    = (float*)(hB + (size_t)n * D);    // G3*D fp32 temp
  _Float16* WxF  = (_Float16*)(Wx + (size_t)G3 * D);  // G3*D fp16 swizzled
  _Float16* WhhF = WxF + (size_t)G3 * D;
  float* bxe   = (float*)(WhhF + (size_t)G3 * D); // G3 fp32
  int* counts  = (int*)(bxe + G3);                // n
  int* fillc   = counts + n;                      // n
  int* row_ptr = fillc + n;                       // n+1
  unsigned short* csr_src = (unsigned short*)(row_ptr + (n + 1));  // E u16
  int* blk_sums = (int*)(csr_src + E);            // <=64  (E even -> aligned)
  int* blk_off  = blk_sums + 64;                  // <=64

  const int threads = 256;
  const int nb = (n + SCAN_BLK - 1) / SCAN_BLK;

  (void)hipMemsetAsync(counts, 0, (size_t)2 * n * sizeof(int), stream);
  hist_kernel<<<(E + threads - 1) / threads, threads, 0, stream>>>(dst, counts, E);
  partial_sum_kernel<<<nb, 256, 0, stream>>>(counts, blk_sums, n);
  scan_offsets_kernel<<<1, 64, 0, stream>>>(blk_sums, blk_off, row_ptr, nb, n);
  block_scan_kernel<<<nb, 256, 0, stream>>>(counts, blk_off, row_ptr, n);
  fill_kernel<<<(E + threads - 1) / threads, threads, 0, stream>>>(src, dst, row_ptr,
                                                                   fillc, csr_src, E);
  compute_wx_kernel<<<(G3 * D + G3 + threads - 1) / threads, threads, 0, stream>>>(
      W_ih, W_e, b_e, Wx, bxe);
  swizzle_f16_kernel<<<(2 * NT * 3 * 64 + threads - 1) / threads, threads, 0, stream>>>(
      Wx, W_hh, WxF, WhhF);
  convert_x_kernel<<<((n * D / 4) + threads - 1) / threads, threads, 0, stream>>>(
      x, hA, n * D / 4);

  const int gridG = (n + 31) / 32;   // 32 rows per block

  const _Float16* hcur = hA;
  _Float16* hnext = hB;
  for (int step = 0; step < NSTEPS; ++step) {
    gru_fused_kernel<<<gridG, 384, 0, stream>>>(hcur, hnext, row_ptr, csr_src,
                                                WxF, WhhF, bxe, b_ih, b_hh, n);
    const _Float16* t = hcur; hcur = hnext; hnext = (_Float16*)t;
  }

  const int gridH = (n * C + threads - 1) / threads;
  head_kernel<<<gridH, threads, 0, stream>>>(hcur, W_fc, b_fc, (float*)d_out, n, C);
}